// Round 1
// baseline (1245.018 us; speedup 1.0000x reference)
//
#include <hip/hip_runtime.h>
#include <hip/hip_bf16.h>

typedef __attribute__((ext_vector_type(8))) short bf16x8;
typedef __attribute__((ext_vector_type(4))) float f32x4;

#define DEVI __device__ __forceinline__

DEVI unsigned short f2bf(float f) {
  union { float f; unsigned u; } v; v.f = f;
  unsigned r = v.u + 0x7FFFu + ((v.u >> 16) & 1u);
  return (unsigned short)(r >> 16);
}

// ---------------- fp32 -> bf16 convert (vectorized, grid-stride) ----------------
__global__ void k_cvt(const float* __restrict__ in, unsigned short* __restrict__ out, int n4) {
  int i = blockIdx.x * blockDim.x + threadIdx.x;
  int stride = gridDim.x * blockDim.x;
  for (; i < n4; i += stride) {
    float4 v = ((const float4*)in)[i];
    ushort4 o;
    o.x = f2bf(v.x); o.y = f2bf(v.y); o.z = f2bf(v.z); o.w = f2bf(v.w);
    ((ushort4*)out)[i] = o;
  }
}

// ------------- transpose [R][C] f32 -> [C][R] bf16, batched over blockIdx.z -------------
__global__ void k_tr(const float* __restrict__ in, unsigned short* __restrict__ out, int R, int C) {
  __shared__ float t[32][33];
  size_t base = (size_t)blockIdx.z * R * C;
  int r0 = blockIdx.y * 32, c0 = blockIdx.x * 32;
  int tx = threadIdx.x, ty = threadIdx.y;
  for (int i = 0; i < 32; i += 8)
    t[ty + i][tx] = in[base + (size_t)(r0 + ty + i) * C + (c0 + tx)];
  __syncthreads();
  for (int i = 0; i < 32; i += 8)
    out[base + (size_t)(c0 + ty + i) * R + (r0 + tx)] = f2bf(t[tx][ty + i]);
}

// ---------------- bf16 MFMA GEMM: C[M,N] = A[M,K] * B[N,K]^T + bias[N] ----------------
// MODE 0: store bf16 row-major [M][N]
// MODE 1: store bf16 V-transposed: out[(col*8 + row/2048)*2048 + row%2048]
// MODE 2: store fp32 row-major [M][N]
template<int MODE>
__global__ __launch_bounds__(256, 2) void k_gemm(
    const unsigned short* __restrict__ A,
    const unsigned short* __restrict__ B,
    const float* __restrict__ bias,
    void* __restrict__ Cout,
    int M, int N, int K)
{
  __shared__ unsigned short ls[2 * 128 * 64];   // A tile 16KB + B tile 16KB
  unsigned short* As = ls;
  unsigned short* Bs = ls + 128 * 64;

  int tid = threadIdx.x;
  int w = tid >> 6, l = tid & 63;
  int lg = l >> 4, lm = l & 15;
  int wr = w >> 1, wc = w & 1;
  int row0 = blockIdx.y * 128, col0 = blockIdx.x * 128;

  const f32x4 fz = {0.f, 0.f, 0.f, 0.f};
  f32x4 acc[4][4];
  for (int i = 0; i < 4; i++) for (int j = 0; j < 4; j++) acc[i][j] = fz;

  int nk = K >> 6;
  for (int t = 0; t < nk; ++t) {
    int k0 = t << 6;
    uint4 ar[4], br[4];
#pragma unroll
    for (int j = 0; j < 4; ++j) {
      int ch = j * 256 + tid;
      int row = ch >> 3, cir = ch & 7;
      ar[j] = *(const uint4*)(A + (size_t)(row0 + row) * K + k0 + cir * 8);
      br[j] = *(const uint4*)(B + (size_t)(col0 + row) * K + k0 + cir * 8);
    }
    __syncthreads();
#pragma unroll
    for (int j = 0; j < 4; ++j) {
      int ch = j * 256 + tid;
      int row = ch >> 3, cir = ch & 7;
      int dst = row * 128 + ((cir * 16) ^ ((row & 7) << 4));
      *(uint4*)((char*)As + dst) = ar[j];
      *(uint4*)((char*)Bs + dst) = br[j];
    }
    __syncthreads();
#pragma unroll
    for (int kt = 0; kt < 2; ++kt) {
      bf16x8 af[4], bf[4];
#pragma unroll
      for (int mi = 0; mi < 4; ++mi) {
        int r = wr * 64 + mi * 16 + lm;
        af[mi] = *(const bf16x8*)((const char*)As + r * 128 + ((kt * 64 + lg * 16) ^ ((r & 7) << 4)));
      }
#pragma unroll
      for (int ni = 0; ni < 4; ++ni) {
        int r = wc * 64 + ni * 16 + lm;
        bf[ni] = *(const bf16x8*)((const char*)Bs + r * 128 + ((kt * 64 + lg * 16) ^ ((r & 7) << 4)));
      }
#pragma unroll
      for (int mi = 0; mi < 4; ++mi)
#pragma unroll
        for (int ni = 0; ni < 4; ++ni)
          acc[mi][ni] = __builtin_amdgcn_mfma_f32_16x16x32_bf16(af[mi], bf[ni], acc[mi][ni], 0, 0, 0);
    }
  }

#pragma unroll
  for (int mi = 0; mi < 4; ++mi) {
#pragma unroll
    for (int ni = 0; ni < 4; ++ni) {
#pragma unroll
      for (int q = 0; q < 4; ++q) {
        int rg = row0 + wr * 64 + mi * 16 + lg * 4 + q;
        int cg = col0 + wc * 64 + ni * 16 + lm;
        float val = acc[mi][ni][q] + bias[cg];
        if (MODE == 0) {
          ((unsigned short*)Cout)[(size_t)rg * N + cg] = f2bf(val);
        } else if (MODE == 1) {
          ((unsigned short*)Cout)[((size_t)cg * 8 + (rg >> 11)) * 2048 + (rg & 2047)] = f2bf(val);
        } else {
          ((float*)Cout)[(size_t)rg * N + cg] = val;
        }
      }
    }
  }
}

// ---------------- flash attention, one block = (n, b, 64 q-rows) ----------------
// Qb,Kb: [b*2048+s][n*256+d] bf16 ; Vt: [(n*256+d)*8+b][s] bf16 ; comb out like Qb.
__global__ __launch_bounds__(256, 2) void k_attn(
    const unsigned short* __restrict__ Qb,
    const unsigned short* __restrict__ Kb,
    const unsigned short* __restrict__ Vt,
    unsigned short* __restrict__ comb)
{
  __shared__ unsigned short Ks[64 * 256];   // [s_local][d], rows 512B, XOR-swizzled
  __shared__ unsigned short Vs[256 * 64];   // [d][s_local], rows 128B, XOR-swizzled
  __shared__ unsigned short Ps[4][16 * 72]; // per-wave P, padded stride 72

  int blk = blockIdx.x;
  int qt = blk & 31, nbb = blk >> 5;
  int n = nbb >> 3, b = nbb & 7;
  int q0 = qt * 64;

  int tid = threadIdx.x;
  int w = tid >> 6, l = tid & 63;
  int lg = l >> 4, lm = l & 15;

  // Q fragments in registers: wave w owns q rows q0+16w .. +16
  bf16x8 qf[8];
  {
    const unsigned short* qbase = Qb + (size_t)(b * 2048 + q0 + w * 16 + lm) * 1024 + n * 256;
#pragma unroll
    for (int kt = 0; kt < 8; ++kt)
      qf[kt] = *(const bf16x8*)(qbase + kt * 32 + lg * 8);
  }

  const f32x4 fz = {0.f, 0.f, 0.f, 0.f};
  f32x4 ao[16];
#pragma unroll
  for (int i = 0; i < 16; ++i) ao[i] = fz;
  float mst[4] = {-1e30f, -1e30f, -1e30f, -1e30f};
  float lst[4] = {0.f, 0.f, 0.f, 0.f};

  const float SL = 0.0625f * 1.44269504088896f;  // scale * log2(e)

  for (int it = 0; it < 32; ++it) {
    int kv0 = it * 64;
    uint4 kr[8], vr[8];
#pragma unroll
    for (int j = 0; j < 8; ++j) {
      int ch = j * 256 + tid;
      { int row = ch >> 5, cir = ch & 31;
        kr[j] = *(const uint4*)(Kb + (size_t)(b * 2048 + kv0 + row) * 1024 + n * 256 + cir * 8); }
      { int row = ch >> 3, cir = ch & 7;
        vr[j] = *(const uint4*)(Vt + ((size_t)(n * 256 + row) * 8 + b) * 2048 + kv0 + cir * 8); }
    }
    __syncthreads();
#pragma unroll
    for (int j = 0; j < 8; ++j) {
      int ch = j * 256 + tid;
      { int row = ch >> 5, cir = ch & 31;
        *(uint4*)((char*)Ks + row * 512 + ((cir * 16) ^ ((row & 7) << 4))) = kr[j]; }
      { int row = ch >> 3, cir = ch & 7;
        *(uint4*)((char*)Vs + row * 128 + ((cir * 16) ^ ((row & 7) << 4))) = vr[j]; }
    }
    __syncthreads();

    // QK^T: sc[ci] = 16x16 tile, rows = wave's q rows, cols = ci*16..+16 of kv tile
    f32x4 sc[4];
#pragma unroll
    for (int ci = 0; ci < 4; ++ci) {
      f32x4 s = fz;
      int krow = ci * 16 + lm;
#pragma unroll
      for (int kt = 0; kt < 8; ++kt) {
        bf16x8 kf = *(const bf16x8*)((const char*)Ks + krow * 512 + ((kt * 64 + lg * 16) ^ ((krow & 7) << 4)));
        s = __builtin_amdgcn_mfma_f32_16x16x32_bf16(qf[kt], kf, s, 0, 0, 0);
      }
      sc[ci] = s;
    }
#pragma unroll
    for (int ci = 0; ci < 4; ++ci)
#pragma unroll
      for (int q = 0; q < 4; ++q) sc[ci][q] *= SL;

    float fq[4];
#pragma unroll
    for (int q = 0; q < 4; ++q) {
      float vm = fmaxf(fmaxf(sc[0][q], sc[1][q]), fmaxf(sc[2][q], sc[3][q]));
#pragma unroll
      for (int d = 1; d < 16; d <<= 1) vm = fmaxf(vm, __shfl_xor(vm, d));
      float mn = fmaxf(mst[q], vm);
      float f = exp2f(mst[q] - mn);
      float p0 = exp2f(sc[0][q] - mn);
      float p1 = exp2f(sc[1][q] - mn);
      float p2 = exp2f(sc[2][q] - mn);
      float p3 = exp2f(sc[3][q] - mn);
      float rs = p0 + p1 + p2 + p3;
#pragma unroll
      for (int d = 1; d < 16; d <<= 1) rs += __shfl_xor(rs, d);
      lst[q] = lst[q] * f + rs;
      mst[q] = mn;
      fq[q] = f;
      int prow = lg * 4 + q;
      Ps[w][prow * 72 + lm +  0] = f2bf(p0);
      Ps[w][prow * 72 + lm + 16] = f2bf(p1);
      Ps[w][prow * 72 + lm + 32] = f2bf(p2);
      Ps[w][prow * 72 + lm + 48] = f2bf(p3);
    }
#pragma unroll
    for (int ni = 0; ni < 16; ++ni)
#pragma unroll
      for (int q = 0; q < 4; ++q) ao[ni][q] *= fq[q];

    // PV: ao[ni] += P[16x64] * V[64 x (ni*16..+16)]
#pragma unroll
    for (int kt = 0; kt < 2; ++kt) {
      bf16x8 pf = *(const bf16x8*)((const char*)&Ps[w][0] + lm * 144 + kt * 64 + lg * 16);
#pragma unroll
      for (int ni = 0; ni < 16; ++ni) {
        int vrow = ni * 16 + lm;
        bf16x8 vf = *(const bf16x8*)((const char*)Vs + vrow * 128 + ((kt * 64 + lg * 16) ^ ((vrow & 7) << 4)));
        ao[ni] = __builtin_amdgcn_mfma_f32_16x16x32_bf16(pf, vf, ao[ni], 0, 0, 0);
      }
    }
  }

#pragma unroll
  for (int q = 0; q < 4; ++q) {
    float rinv = 1.0f / lst[q];
    int srow = q0 + w * 16 + lg * 4 + q;
    size_t rowbase = (size_t)(b * 2048 + srow) * 1024 + n * 256;
#pragma unroll
    for (int ni = 0; ni < 16; ++ni)
      comb[rowbase + ni * 16 + lm] = f2bf(ao[ni][q] * rinv);
  }
}

extern "C" void kernel_launch(void* const* d_in, const int* in_sizes, int n_in,
                              void* d_out, int out_size, void* d_ws, size_t ws_size,
                              hipStream_t stream) {
  const float* x  = (const float*)d_in[0];
  const float* Wq = (const float*)d_in[1];
  const float* bq = (const float*)d_in[2];
  const float* Wk = (const float*)d_in[3];
  const float* bk = (const float*)d_in[4];
  const float* Wv = (const float*)d_in[5];
  const float* bv = (const float*)d_in[6];
  const float* Wo = (const float*)d_in[7];
  const float* bo = (const float*)d_in[8];

  const size_t MB = 1ull << 20;
  char* ws = (char*)d_ws;
  unsigned short* xb  = (unsigned short*)(ws);            // 32MB (reused as comb)
  unsigned short* Wqt = (unsigned short*)(ws + 32 * MB);  // 2MB
  unsigned short* Wkt = (unsigned short*)(ws + 34 * MB);  // 2MB
  unsigned short* Wvt = (unsigned short*)(ws + 36 * MB);  // 2MB
  unsigned short* Wot = (unsigned short*)(ws + 38 * MB);  // 0.5MB
  unsigned short* Qb  = (unsigned short*)(ws + 40 * MB);  // 32MB
  unsigned short* Kb  = (unsigned short*)(ws + 72 * MB);  // 32MB
  unsigned short* Vt  = (unsigned short*)(ws + 104 * MB); // 32MB (end: 136MB)
  unsigned short* comb = xb;

  k_cvt<<<2048, 256, 0, stream>>>(x, xb, 16384 * 1024 / 4);
  dim3 trb(32, 8);
  k_tr<<<dim3(8, 32, 4), trb, 0, stream>>>(Wq, Wqt, 1024, 256);
  k_tr<<<dim3(8, 32, 4), trb, 0, stream>>>(Wk, Wkt, 1024, 256);
  k_tr<<<dim3(8, 32, 4), trb, 0, stream>>>(Wv, Wvt, 1024, 256);
  k_tr<<<dim3(8, 32, 1), trb, 0, stream>>>(Wo, Wot, 1024, 256);

  k_gemm<0><<<dim3(8, 128), 256, 0, stream>>>(xb, Wqt, bq, Qb, 16384, 1024, 1024);
  k_gemm<0><<<dim3(8, 128), 256, 0, stream>>>(xb, Wkt, bk, Kb, 16384, 1024, 1024);
  k_gemm<1><<<dim3(8, 128), 256, 0, stream>>>(xb, Wvt, bv, Vt, 16384, 1024, 1024);

  k_attn<<<1024, 256, 0, stream>>>(Qb, Kb, Vt, comb);

  k_gemm<2><<<dim3(2, 128), 256, 0, stream>>>(comb, Wot, bo, d_out, 16384, 256, 1024);
}

// Round 2
// 960.838 us; speedup vs baseline: 1.2958x; 1.2958x over previous
//
#include <hip/hip_runtime.h>
#include <hip/hip_bf16.h>

typedef __attribute__((ext_vector_type(8))) short bf16x8;
typedef __attribute__((ext_vector_type(4))) float f32x4;
typedef __attribute__((ext_vector_type(16))) float f32x16;

#define DEVI __device__ __forceinline__

DEVI unsigned short f2bf(float f) {
  union { float f; unsigned u; } v; v.f = f;
  unsigned r = v.u + 0x7FFFu + ((v.u >> 16) & 1u);
  return (unsigned short)(r >> 16);
}

// ---------------- fp32 -> bf16 convert (vectorized, grid-stride) ----------------
__global__ void k_cvt(const float* __restrict__ in, unsigned short* __restrict__ out, int n4) {
  int i = blockIdx.x * blockDim.x + threadIdx.x;
  int stride = gridDim.x * blockDim.x;
  for (; i < n4; i += stride) {
    float4 v = ((const float4*)in)[i];
    ushort4 o;
    o.x = f2bf(v.x); o.y = f2bf(v.y); o.z = f2bf(v.z); o.w = f2bf(v.w);
    ((ushort4*)out)[i] = o;
  }
}

// ------------- transpose [R][C] f32 -> [C][R] bf16, batched over blockIdx.z -------------
__global__ void k_tr(const float* __restrict__ in, unsigned short* __restrict__ out, int R, int C) {
  __shared__ float t[32][33];
  size_t base = (size_t)blockIdx.z * R * C;
  int r0 = blockIdx.y * 32, c0 = blockIdx.x * 32;
  int tx = threadIdx.x, ty = threadIdx.y;
  for (int i = 0; i < 32; i += 8)
    t[ty + i][tx] = in[base + (size_t)(r0 + ty + i) * C + (c0 + tx)];
  __syncthreads();
  for (int i = 0; i < 32; i += 8)
    out[base + (size_t)(c0 + ty + i) * R + (r0 + tx)] = f2bf(t[tx][ty + i]);
}

// ---------------- bf16 MFMA GEMM: C[M,N] = (A[M,K] * B[N,K]^T + bias[N]) * oscale ----------------
// MODE 0: store bf16 row-major [M][N]
// MODE 1: store bf16 V-transposed + kv bit2<->3 permute:
//         out[(col*8 + row/2048)*2048 + perm(row%2048)]
// MODE 2: store fp32 row-major [M][N]
template<int MODE>
__global__ __launch_bounds__(256, 2) void k_gemm(
    const unsigned short* __restrict__ A,
    const unsigned short* __restrict__ B,
    const float* __restrict__ bias,
    void* __restrict__ Cout,
    int M, int N, int K, float oscale)
{
  __shared__ unsigned short ls[2 * 128 * 64];   // A tile 16KB + B tile 16KB
  unsigned short* As = ls;
  unsigned short* Bs = ls + 128 * 64;

  int tid = threadIdx.x;
  int w = tid >> 6, l = tid & 63;
  int lg = l >> 4, lm = l & 15;
  int wr = w >> 1, wc = w & 1;
  int row0 = blockIdx.y * 128, col0 = blockIdx.x * 128;

  const f32x4 fz = {0.f, 0.f, 0.f, 0.f};
  f32x4 acc[4][4];
  for (int i = 0; i < 4; i++) for (int j = 0; j < 4; j++) acc[i][j] = fz;

  int nk = K >> 6;
  for (int t = 0; t < nk; ++t) {
    int k0 = t << 6;
    uint4 ar[4], br[4];
#pragma unroll
    for (int j = 0; j < 4; ++j) {
      int ch = j * 256 + tid;
      int row = ch >> 3, cir = ch & 7;
      ar[j] = *(const uint4*)(A + (size_t)(row0 + row) * K + k0 + cir * 8);
      br[j] = *(const uint4*)(B + (size_t)(col0 + row) * K + k0 + cir * 8);
    }
    __syncthreads();
#pragma unroll
    for (int j = 0; j < 4; ++j) {
      int ch = j * 256 + tid;
      int row = ch >> 3, cir = ch & 7;
      int dst = row * 128 + ((cir * 16) ^ ((row & 7) << 4));
      *(uint4*)((char*)As + dst) = ar[j];
      *(uint4*)((char*)Bs + dst) = br[j];
    }
    __syncthreads();
#pragma unroll
    for (int kt = 0; kt < 2; ++kt) {
      bf16x8 af[4], bf[4];
#pragma unroll
      for (int mi = 0; mi < 4; ++mi) {
        int r = wr * 64 + mi * 16 + lm;
        af[mi] = *(const bf16x8*)((const char*)As + r * 128 + ((kt * 64 + lg * 16) ^ ((r & 7) << 4)));
      }
#pragma unroll
      for (int ni = 0; ni < 4; ++ni) {
        int r = wc * 64 + ni * 16 + lm;
        bf[ni] = *(const bf16x8*)((const char*)Bs + r * 128 + ((kt * 64 + lg * 16) ^ ((r & 7) << 4)));
      }
#pragma unroll
      for (int mi = 0; mi < 4; ++mi)
#pragma unroll
        for (int ni = 0; ni < 4; ++ni)
          acc[mi][ni] = __builtin_amdgcn_mfma_f32_16x16x32_bf16(af[mi], bf[ni], acc[mi][ni], 0, 0, 0);
    }
  }

#pragma unroll
  for (int mi = 0; mi < 4; ++mi) {
#pragma unroll
    for (int ni = 0; ni < 4; ++ni) {
#pragma unroll
      for (int q = 0; q < 4; ++q) {
        int rg = row0 + wr * 64 + mi * 16 + lg * 4 + q;
        int cg = col0 + wc * 64 + ni * 16 + lm;
        float val = (acc[mi][ni][q] + bias[cg]) * oscale;
        if (MODE == 0) {
          ((unsigned short*)Cout)[(size_t)rg * N + cg] = f2bf(val);
        } else if (MODE == 1) {
          int s = rg & 2047;
          int sp = (s & ~15) | (((s >> 2) & 1) << 3) | (((s >> 3) & 1) << 2) | (s & 3);
          ((unsigned short*)Cout)[((size_t)cg * 8 + (rg >> 11)) * 2048 + sp] = f2bf(val);
        } else {
          ((float*)Cout)[(size_t)rg * N + cg] = val;
        }
      }
    }
  }
}

// ---------------- flash attention ----------------
// 8 waves, block = 128 q rows of one (n,b). Wave w: q-group w&3 (32 rows),
// d-half w>>2 (128 cols of PV output). Swapped QK^T (mfma(K,Q)) with 32x32x16,
// P in registers, V pre-permuted (kv bits 2<->3) so PV B-frags are contiguous b128.
__global__ __launch_bounds__(512, 2) void k_attn(
    const unsigned short* __restrict__ Qb,
    const unsigned short* __restrict__ Kb,
    const unsigned short* __restrict__ Vt,
    unsigned short* __restrict__ comb)
{
  __shared__ unsigned short Ks[64 * 256];   // [kv][d] rows 512B, 16B-slot XOR swizzle
  __shared__ unsigned short Vs[256 * 64];   // [d][kv'] rows 128B, 16B-slot XOR swizzle

  // XCD-sequential mapping: XCD c works through (n,b) = c, c+8, c+16, c+24 in order.
  int i = blockIdx.x;
  int c = i & 7, j = i >> 3;
  int nbb = c + 8 * (j >> 4);
  int qt = j & 15;
  int n = nbb >> 3, b = nbb & 7;
  int q0 = qt * 128;

  int tid = threadIdx.x;
  int w = tid >> 6, l = tid & 63;
  int m = l & 31, g = l >> 5;
  int qg = w & 3, dh = w >> 2;
  int sw = (m & 7) << 4;

  // Q fragments: rows q0+qg*32+m, all 256 d; k-packing d = ks*16 + g*8 + j.
  bf16x8 qf[16];
  {
    const unsigned short* qbase = Qb + (size_t)(b * 2048 + q0 + qg * 32 + m) * 1024 + n * 256 + g * 8;
#pragma unroll
    for (int ks = 0; ks < 16; ++ks)
      qf[ks] = *(const bf16x8*)(qbase + ks * 16);
  }

  f32x16 ao[4];
#pragma unroll
  for (int dt = 0; dt < 4; ++dt)
#pragma unroll
    for (int r = 0; r < 16; ++r) ao[dt][r] = 0.f;
  float m_s = -1e30f, l_s = 0.f;

  // staging: per wave K rows w*8..+8 (4x uint4/lane), V rows w*32..+32 (4x uint4/lane)
  const unsigned short* kp0 = Kb + (size_t)(b * 2048 + w * 8 + (l >> 5)) * 1024 + n * 256 + (l & 31) * 8;
  const unsigned short* vp0 = Vt + ((size_t)(n * 256 + w * 32 + (l >> 3)) * 8 + b) * 2048 + (l & 7) * 8;

  uint4 kst[4], vst[4];
#pragma unroll
  for (int jj = 0; jj < 4; ++jj) {
    kst[jj] = *(const uint4*)(kp0 + jj * 2048);
    vst[jj] = *(const uint4*)(vp0 + jj * 131072);
  }
#pragma unroll
  for (int jj = 0; jj < 4; ++jj) {
    int kr = w * 8 + jj * 2 + (l >> 5);
    *(uint4*)((char*)Ks + kr * 512 + (((l & 31) * 16) ^ ((kr & 7) << 4))) = kst[jj];
    int vd = w * 32 + jj * 8 + (l >> 3);
    *(uint4*)((char*)Vs + vd * 128 + (((l & 7) * 16) ^ ((vd & 7) << 4))) = vst[jj];
  }
  __syncthreads();

  for (int t = 0; t < 32; ++t) {
    if (t < 31) {
      int kv1 = (t + 1) * 64;
#pragma unroll
      for (int jj = 0; jj < 4; ++jj) {
        kst[jj] = *(const uint4*)(kp0 + (size_t)kv1 * 1024 + jj * 2048);
        vst[jj] = *(const uint4*)(vp0 + kv1 + jj * 131072);
      }
    }

    // QK^T swapped: s0/s1 = S[kv 0..31 / 32..63][q], q = col = lane&31
    f32x16 s0, s1;
#pragma unroll
    for (int r = 0; r < 16; ++r) { s0[r] = 0.f; s1[r] = 0.f; }
#pragma unroll
    for (int ks = 0; ks < 16; ++ks) {
      bf16x8 k0 = *(const bf16x8*)((const char*)Ks + m * 512 + ((ks * 32 + g * 16) ^ sw));
      bf16x8 k1 = *(const bf16x8*)((const char*)Ks + (32 + m) * 512 + ((ks * 32 + g * 16) ^ sw));
      s0 = __builtin_amdgcn_mfma_f32_32x32x16_bf16(k0, qf[ks], s0, 0, 0, 0);
      s1 = __builtin_amdgcn_mfma_f32_32x32x16_bf16(k1, qf[ks], s1, 0, 0, 0);
    }

    // online softmax (scores already in exp2 domain via Q pre-scale)
    float vm = s0[0];
#pragma unroll
    for (int r = 1; r < 16; ++r) vm = fmaxf(vm, s0[r]);
#pragma unroll
    for (int r = 0; r < 16; ++r) vm = fmaxf(vm, s1[r]);
    vm = fmaxf(vm, __shfl_xor(vm, 32));

    if (__any(vm > m_s + 8.f)) {
      float mn = fmaxf(m_s, vm);
      float f = exp2f(m_s - mn);
      m_s = mn; l_s *= f;
#pragma unroll
      for (int r = 0; r < 16; ++r) {
        float fr = __shfl(f, 4 * g + (r & 3) + 8 * (r >> 2));
        ao[0][r] *= fr; ao[1][r] *= fr; ao[2][r] *= fr; ao[3][r] *= fr;
      }
    }

    float p0[16], p1[16];
    float rs = 0.f;
#pragma unroll
    for (int r = 0; r < 16; ++r) {
      p0[r] = exp2f(s0[r] - m_s);
      p1[r] = exp2f(s1[r] - m_s);
      rs += p0[r] + p1[r];
    }
    rs += __shfl_xor(rs, 32);
    l_s += rs;

    // pack P into A-frags: pa[ks2] elem j <- P[kv = ks2*16 + 8*(j>>2) + 4g + (j&3)]
    bf16x8 pa[4];
#pragma unroll
    for (int ks2 = 0; ks2 < 4; ++ks2) {
#pragma unroll
      for (int jj = 0; jj < 8; ++jj) {
        int ridx = ((ks2 & 1) * 2 + (jj >> 2)) * 4 + (jj & 3);
        float pv = (ks2 < 2) ? p0[ridx] : p1[ridx];
        pa[ks2][jj] = (short)f2bf(pv);
      }
    }

    // PV: ao[dt] += P[q32][kv64] * V[kv64][d32 tile]
#pragma unroll
    for (int dt = 0; dt < 4; ++dt) {
      int vrow = dh * 128 + dt * 32 + m;
#pragma unroll
      for (int ks2 = 0; ks2 < 4; ++ks2) {
        bf16x8 vf = *(const bf16x8*)((const char*)Vs + vrow * 128 + ((ks2 * 32 + g * 16) ^ sw));
        ao[dt] = __builtin_amdgcn_mfma_f32_32x32x16_bf16(pa[ks2], vf, ao[dt], 0, 0, 0);
      }
    }

    __syncthreads();
    if (t < 31) {
#pragma unroll
      for (int jj = 0; jj < 4; ++jj) {
        int kr = w * 8 + jj * 2 + (l >> 5);
        *(uint4*)((char*)Ks + kr * 512 + (((l & 31) * 16) ^ ((kr & 7) << 4))) = kst[jj];
        int vd = w * 32 + jj * 8 + (l >> 3);
        *(uint4*)((char*)Vs + vd * 128 + (((l & 7) * 16) ^ ((vd & 7) << 4))) = vst[jj];
      }
      __syncthreads();
    }
  }

  // epilogue: normalize by l and store
  float rinv[16];
#pragma unroll
  for (int r = 0; r < 16; ++r) {
    float lr = __shfl(l_s, 4 * g + (r & 3) + 8 * (r >> 2));
    rinv[r] = 1.f / lr;
  }
#pragma unroll
  for (int dt = 0; dt < 4; ++dt) {
    int col = n * 256 + dh * 128 + dt * 32 + m;
#pragma unroll
    for (int r = 0; r < 16; ++r) {
      int rowq = q0 + qg * 32 + 4 * g + (r & 3) + 8 * (r >> 2);
      comb[(size_t)(b * 2048 + rowq) * 1024 + col] = f2bf(ao[dt][r] * rinv[r]);
    }
  }
}

extern "C" void kernel_launch(void* const* d_in, const int* in_sizes, int n_in,
                              void* d_out, int out_size, void* d_ws, size_t ws_size,
                              hipStream_t stream) {
  const float* x  = (const float*)d_in[0];
  const float* Wq = (const float*)d_in[1];
  const float* bq = (const float*)d_in[2];
  const float* Wk = (const float*)d_in[3];
  const float* bk = (const float*)d_in[4];
  const float* Wv = (const float*)d_in[5];
  const float* bv = (const float*)d_in[6];
  const float* Wo = (const float*)d_in[7];
  const float* bo = (const float*)d_in[8];

  const size_t MB = 1ull << 20;
  char* ws = (char*)d_ws;
  unsigned short* xb  = (unsigned short*)(ws);            // 32MB (reused as comb)
  unsigned short* Wqt = (unsigned short*)(ws + 32 * MB);  // 2MB
  unsigned short* Wkt = (unsigned short*)(ws + 34 * MB);  // 2MB
  unsigned short* Wvt = (unsigned short*)(ws + 36 * MB);  // 2MB
  unsigned short* Wot = (unsigned short*)(ws + 38 * MB);  // 0.5MB
  unsigned short* Qb  = (unsigned short*)(ws + 40 * MB);  // 32MB
  unsigned short* Kb  = (unsigned short*)(ws + 72 * MB);  // 32MB
  unsigned short* Vt  = (unsigned short*)(ws + 104 * MB); // 32MB (end: 136MB)
  unsigned short* comb = xb;

  k_cvt<<<2048, 256, 0, stream>>>(x, xb, 16384 * 1024 / 4);
  dim3 trb(32, 8);
  k_tr<<<dim3(8, 32, 4), trb, 0, stream>>>(Wq, Wqt, 1024, 256);
  k_tr<<<dim3(8, 32, 4), trb, 0, stream>>>(Wk, Wkt, 1024, 256);
  k_tr<<<dim3(8, 32, 4), trb, 0, stream>>>(Wv, Wvt, 1024, 256);
  k_tr<<<dim3(8, 32, 1), trb, 0, stream>>>(Wo, Wot, 1024, 256);

  const float qscale = 0.0625f * 1.44269504088896f;  // 1/sqrt(256) * log2(e)
  k_gemm<0><<<dim3(8, 128), 256, 0, stream>>>(xb, Wqt, bq, Qb, 16384, 1024, 1024, qscale);
  k_gemm<0><<<dim3(8, 128), 256, 0, stream>>>(xb, Wkt, bk, Kb, 16384, 1024, 1024, 1.0f);
  k_gemm<1><<<dim3(8, 128), 256, 0, stream>>>(xb, Wvt, bv, Vt, 16384, 1024, 1024, 1.0f);

  k_attn<<<512, 512, 0, stream>>>(Qb, Kb, Vt, comb);

  k_gemm<2><<<dim3(2, 128), 256, 0, stream>>>(comb, Wot, bo, d_out, 16384, 256, 1024, 1.0f);
}

// Round 4
// 434.941 us; speedup vs baseline: 2.8625x; 2.2091x over previous
//
#include <hip/hip_runtime.h>
#include <hip/hip_bf16.h>

typedef __attribute__((ext_vector_type(8))) short bf16x8;
typedef __attribute__((ext_vector_type(4))) float f32x4;
typedef __attribute__((ext_vector_type(16))) float f32x16;

#define DEVI __device__ __forceinline__

DEVI unsigned short f2bf(float f) {
  union { float f; unsigned u; } v; v.f = f;
  unsigned r = v.u + 0x7FFFu + ((v.u >> 16) & 1u);
  return (unsigned short)(r >> 16);
}

DEVI void gload16(const void* g, void* l) {
  __builtin_amdgcn_global_load_lds(
      (const __attribute__((address_space(1))) unsigned int*)g,
      (__attribute__((address_space(3))) unsigned int*)l, 16, 0, 0);
}

// ---------------- fp32 -> bf16 convert ----------------
__global__ void k_cvt(const float* __restrict__ in, unsigned short* __restrict__ out, int n4) {
  int i = blockIdx.x * blockDim.x + threadIdx.x;
  int stride = gridDim.x * blockDim.x;
  for (; i < n4; i += stride) {
    float4 v = ((const float4*)in)[i];
    ushort4 o;
    o.x = f2bf(v.x); o.y = f2bf(v.y); o.z = f2bf(v.z); o.w = f2bf(v.w);
    ((ushort4*)out)[i] = o;
  }
}

// ------------- transpose [R][C] f32 -> [C][R] bf16, batched over blockIdx.z -------------
__global__ void k_tr(const float* __restrict__ in, unsigned short* __restrict__ out, int R, int C) {
  __shared__ float t[32][33];
  size_t base = (size_t)blockIdx.z * R * C;
  int r0 = blockIdx.y * 32, c0 = blockIdx.x * 32;
  int tx = threadIdx.x, ty = threadIdx.y;
  for (int i = 0; i < 32; i += 8)
    t[ty + i][tx] = in[base + (size_t)(r0 + ty + i) * C + (c0 + tx)];
  __syncthreads();
  for (int i = 0; i < 32; i += 8)
    out[base + (size_t)(c0 + ty + i) * R + (r0 + tx)] = f2bf(t[tx][ty + i]);
}

// ---------------- fused QKV GEMM: [16384,1024] x [3072,1024]^T ----------------
// 128x256 tile, 512 thr, global_load_lds staging (linear LDS, source-permuted swizzle).
// Epilogue per column-range: Q (bf16 rowmajor, *qscale), K (fragment-plane layout),
// V (transposed + kv bit2<->3 permute).
__global__ __launch_bounds__(512, 4) void k_gemmqkv(
    const unsigned short* __restrict__ A,
    const unsigned short* __restrict__ B,
    const float* __restrict__ bq, const float* __restrict__ bk,
    const float* __restrict__ bv,
    unsigned short* __restrict__ Qb, unsigned short* __restrict__ Kg,
    unsigned short* __restrict__ Vt, float qscale)
{
  __shared__ unsigned short As[128 * 64];
  __shared__ unsigned short Bs[256 * 64];
  int tid = threadIdx.x;
  int w = tid >> 6, l = tid & 63;
  int lg = l >> 4, lm = l & 15;
  int wr = w >> 2, wc = w & 3;
  int row0 = blockIdx.y * 128, col0 = blockIdx.x * 256;

  const f32x4 fz = {0.f, 0.f, 0.f, 0.f};
  f32x4 acc[4][4];
  for (int i = 0; i < 4; i++) for (int j = 0; j < 4; j++) acc[i][j] = fz;

  for (int t = 0; t < 16; ++t) {
    int k0 = t << 6;
    __syncthreads();
#pragma unroll
    for (int j = 0; j < 2; ++j) {
      int ch = j * 512 + tid;
      int row = ch >> 3, cirp = (ch & 7) ^ (row & 7);
      gload16(A + (size_t)(row0 + row) * 1024 + k0 + cirp * 8,
              As + (size_t)(j * 512 + w * 64) * 8);
    }
#pragma unroll
    for (int j = 0; j < 4; ++j) {
      int ch = j * 512 + tid;
      int row = ch >> 3, cirp = (ch & 7) ^ (row & 7);
      gload16(B + (size_t)(col0 + row) * 1024 + k0 + cirp * 8,
              Bs + (size_t)(j * 512 + w * 64) * 8);
    }
    __syncthreads();
#pragma unroll
    for (int kt = 0; kt < 2; ++kt) {
      bf16x8 bfr[4];
#pragma unroll
      for (int ni = 0; ni < 4; ++ni) {
        int r = wc * 64 + ni * 16 + lm;
        bfr[ni] = *(const bf16x8*)((const char*)Bs + r * 128 + ((kt * 64 + lg * 16) ^ ((r & 7) << 4)));
      }
#pragma unroll
      for (int mi = 0; mi < 4; ++mi) {
        int r = wr * 64 + mi * 16 + lm;
        bf16x8 afr = *(const bf16x8*)((const char*)As + r * 128 + ((kt * 64 + lg * 16) ^ ((r & 7) << 4)));
#pragma unroll
        for (int ni = 0; ni < 4; ++ni)
          acc[mi][ni] = __builtin_amdgcn_mfma_f32_16x16x32_bf16(afr, bfr[ni], acc[mi][ni], 0, 0, 0);
      }
    }
  }

  int sel = col0 >> 10;                 // block-uniform: 0=Q, 1=K, 2=V
  const float* bb = sel == 0 ? bq : (sel == 1 ? bk : bv);
#pragma unroll
  for (int mi = 0; mi < 4; ++mi) {
#pragma unroll
    for (int ni = 0; ni < 4; ++ni) {
#pragma unroll
      for (int q = 0; q < 4; ++q) {
        int rg = row0 + wr * 64 + mi * 16 + lg * 4 + q;
        int cg = col0 + wc * 64 + ni * 16 + lm;
        int cl = cg & 1023;
        float val = acc[mi][ni][q] + bb[cl];
        int bI = rg >> 11, s = rg & 2047;
        int nn = cl >> 8, d = cl & 255;
        if (sel == 0) {
          Qb[(size_t)rg * 1024 + cl] = f2bf(val * qscale);
        } else if (sel == 1) {
          Kg[((size_t)((nn * 8 + bI) * 32 + (d >> 3))) * 16384 + (size_t)s * 8 + (d & 7)] = f2bf(val);
        } else {
          int sp = (s & ~15) | (((s >> 2) & 1) << 3) | (((s >> 3) & 1) << 2) | (s & 3);
          Vt[((size_t)(nn * 256 + d) * 8 + bI) * 2048 + sp] = f2bf(val);
        }
      }
    }
  }
}

// ---------------- output GEMM: [16384,1024] x [256,1024]^T -> fp32 + bo ----------------
__global__ __launch_bounds__(512, 4) void k_gemmo(
    const unsigned short* __restrict__ A,
    const unsigned short* __restrict__ B,
    const float* __restrict__ bias,
    float* __restrict__ Cout)
{
  __shared__ unsigned short As[128 * 64];
  __shared__ unsigned short Bs[256 * 64];
  int tid = threadIdx.x;
  int w = tid >> 6, l = tid & 63;
  int lg = l >> 4, lm = l & 15;
  int wr = w >> 2, wc = w & 3;
  int row0 = blockIdx.y * 128;

  const f32x4 fz = {0.f, 0.f, 0.f, 0.f};
  f32x4 acc[4][4];
  for (int i = 0; i < 4; i++) for (int j = 0; j < 4; j++) acc[i][j] = fz;

  for (int t = 0; t < 16; ++t) {
    int k0 = t << 6;
    __syncthreads();
#pragma unroll
    for (int j = 0; j < 2; ++j) {
      int ch = j * 512 + tid;
      int row = ch >> 3, cirp = (ch & 7) ^ (row & 7);
      gload16(A + (size_t)(row0 + row) * 1024 + k0 + cirp * 8,
              As + (size_t)(j * 512 + w * 64) * 8);
    }
#pragma unroll
    for (int j = 0; j < 4; ++j) {
      int ch = j * 512 + tid;
      int row = ch >> 3, cirp = (ch & 7) ^ (row & 7);
      gload16(B + (size_t)(row) * 1024 + k0 + cirp * 8,
              Bs + (size_t)(j * 512 + w * 64) * 8);
    }
    __syncthreads();
#pragma unroll
    for (int kt = 0; kt < 2; ++kt) {
      bf16x8 bfr[4];
#pragma unroll
      for (int ni = 0; ni < 4; ++ni) {
        int r = wc * 64 + ni * 16 + lm;
        bfr[ni] = *(const bf16x8*)((const char*)Bs + r * 128 + ((kt * 64 + lg * 16) ^ ((r & 7) << 4)));
      }
#pragma unroll
      for (int mi = 0; mi < 4; ++mi) {
        int r = wr * 64 + mi * 16 + lm;
        bf16x8 afr = *(const bf16x8*)((const char*)As + r * 128 + ((kt * 64 + lg * 16) ^ ((r & 7) << 4)));
#pragma unroll
        for (int ni = 0; ni < 4; ++ni)
          acc[mi][ni] = __builtin_amdgcn_mfma_f32_16x16x32_bf16(afr, bfr[ni], acc[mi][ni], 0, 0, 0);
      }
    }
  }

#pragma unroll
  for (int mi = 0; mi < 4; ++mi)
#pragma unroll
    for (int ni = 0; ni < 4; ++ni)
#pragma unroll
      for (int q = 0; q < 4; ++q) {
        int rg = row0 + wr * 64 + mi * 16 + lg * 4 + q;
        int cg = wc * 64 + ni * 16 + lm;
        Cout[(size_t)rg * 256 + cg] = acc[mi][ni][q] + bias[cg];
      }
}

// ---------------- flash attention ----------------
// block = 128 q rows of one (n,b); 8 waves: qg=w&3 (32 q rows), dh=w>>2 (d half).
// K LDS plane-major [dslot 32][kv 64][16B]; V LDS plane-major [kvslot 8][d 256][16B].
// Double-buffered, ONE barrier per kv-iter. All LDS accesses conflict-free.
__global__ __launch_bounds__(512, 2) void k_attn(
    const unsigned short* __restrict__ Qb,
    const unsigned short* __restrict__ Kg,
    const unsigned short* __restrict__ Vt,
    unsigned short* __restrict__ comb)
{
  __shared__ unsigned short Ks[2][32 * 64 * 8];
  __shared__ unsigned short Vs[2][8 * 256 * 8];

  int i = blockIdx.x;
  int c = i & 7, j = i >> 3;
  int nbb = c + 8 * (j >> 4);
  int qt = j & 15;
  int n = nbb >> 3, b = nbb & 7;
  int q0 = qt * 128;

  int tid = threadIdx.x;
  int w = tid >> 6, l = tid & 63;
  int m = l & 31, g = l >> 5;
  int qg = w & 3, dh = w >> 2;

  // Q fragments: rows q0+qg*32+m, k-pack d = ks*16 + g*8 + j
  bf16x8 qf[16];
  {
    const unsigned short* qbase = Qb + (size_t)(b * 2048 + q0 + qg * 32 + m) * 1024 + n * 256 + g * 8;
#pragma unroll
    for (int ks = 0; ks < 16; ++ks)
      qf[ks] = *(const bf16x8*)(qbase + ks * 16);
  }

  f32x16 ao[4];
#pragma unroll
  for (int dt = 0; dt < 4; ++dt)
#pragma unroll
    for (int r = 0; r < 16; ++r) ao[dt][r] = 0.f;
  float m_s = -1e30f, l_s = 0.f;

  // staging pointers: K plane w*4+jj over kv=l; V d-rows w*32+jj*8+(l>>3), kvslot l&7
  const unsigned short* kp0 = Kg + ((size_t)(n * 8 + b) * 32 + w * 4) * 16384 + (size_t)l * 8;
  const unsigned short* vp0 = Vt + ((size_t)(n * 256 + w * 32 + (l >> 3)) * 8 + b) * 2048 + (l & 7) * 8;

  uint4 kst[4], vst[4];
#pragma unroll
  for (int jj = 0; jj < 4; ++jj) {
    kst[jj] = *(const uint4*)(kp0 + (size_t)jj * 16384);
    vst[jj] = *(const uint4*)(vp0 + (size_t)jj * 131072);
  }
#pragma unroll
  for (int jj = 0; jj < 4; ++jj) {
    *(uint4*)((char*)Ks[0] + ((w * 4 + jj) * 64 + l) * 16) = kst[jj];
    *(uint4*)((char*)Vs[0] + ((l & 7) * 256 + w * 32 + jj * 8 + (l >> 3)) * 16) = vst[jj];
  }
  __syncthreads();

  for (int t = 0; t < 32; ++t) {
    int cur = t & 1;
    const unsigned short* Kc = Ks[cur];
    const unsigned short* Vc = Vs[cur];

    if (t < 31) {
      int kv1 = (t + 1) * 64;
#pragma unroll
      for (int jj = 0; jj < 4; ++jj) {
        kst[jj] = *(const uint4*)(kp0 + (size_t)jj * 16384 + (size_t)kv1 * 8);
        vst[jj] = *(const uint4*)(vp0 + (size_t)jj * 131072 + kv1);
      }
    }

    // QK^T swapped: s0/s1 = S[kv 0..31 / 32..63][q=lane&31]
    f32x16 s0, s1;
#pragma unroll
    for (int r = 0; r < 16; ++r) { s0[r] = 0.f; s1[r] = 0.f; }
    __builtin_amdgcn_s_setprio(1);
#pragma unroll
    for (int ks = 0; ks < 16; ++ks) {
      bf16x8 k0 = *(const bf16x8*)(Kc + ((2 * ks + g) * 64 + m) * 8);
      bf16x8 k1 = *(const bf16x8*)(Kc + ((2 * ks + g) * 64 + 32 + m) * 8);
      s0 = __builtin_amdgcn_mfma_f32_32x32x16_bf16(k0, qf[ks], s0, 0, 0, 0);
      s1 = __builtin_amdgcn_mfma_f32_32x32x16_bf16(k1, qf[ks], s1, 0, 0, 0);
    }
    __builtin_amdgcn_s_setprio(0);

    // online softmax (exp2 domain; Q pre-scaled)
    float vm = s0[0];
#pragma unroll
    for (int r = 1; r < 16; ++r) vm = fmaxf(vm, s0[r]);
#pragma unroll
    for (int r = 0; r < 16; ++r) vm = fmaxf(vm, s1[r]);
    vm = fmaxf(vm, __shfl_xor(vm, 32));

    if (__any(vm > m_s + 8.f)) {
      float mn = fmaxf(m_s, vm);
      float f = exp2f(m_s - mn);
      m_s = mn; l_s *= f;
#pragma unroll
      for (int r = 0; r < 16; ++r) {
        float fr = __shfl(f, 4 * g + (r & 3) + 8 * (r >> 2));
        ao[0][r] *= fr; ao[1][r] *= fr; ao[2][r] *= fr; ao[3][r] *= fr;
      }
    }

    float p0[16], p1[16];
    float rs = 0.f;
#pragma unroll
    for (int r = 0; r < 16; ++r) {
      p0[r] = exp2f(s0[r] - m_s);
      p1[r] = exp2f(s1[r] - m_s);
      rs += p0[r] + p1[r];
    }
    rs += __shfl_xor(rs, 32);
    l_s += rs;

    // pack P: pa[ks2] elem j <- P[kv = ks2*16 + 8*(j>>2) + 4g + (j&3)]
    bf16x8 pa[4];
#pragma unroll
    for (int ks2 = 0; ks2 < 4; ++ks2) {
#pragma unroll
      for (int jj = 0; jj < 8; ++jj) {
        int ridx = ((ks2 & 1) * 2 + (jj >> 2)) * 4 + (jj & 3);
        float pv = (ks2 < 2) ? p0[ridx] : p1[ridx];
        pa[ks2][jj] = (short)f2bf(pv);
      }
    }

    // PV: ao[dt] += P[q32][kv64] * V[kv64][d32]
    __builtin_amdgcn_s_setprio(1);
#pragma unroll
    for (int dt = 0; dt < 4; ++dt) {
      int vrow = dh * 128 + dt * 32 + m;
#pragma unroll
      for (int ks2 = 0; ks2 < 4; ++ks2) {
        bf16x8 vf = *(const bf16x8*)(Vc + ((2 * ks2 + g) * 256 + vrow) * 8);
        ao[dt] = __builtin_amdgcn_mfma_f32_32x32x16_bf16(pa[ks2], vf, ao[dt], 0, 0, 0);
      }
    }
    __builtin_amdgcn_s_setprio(0);

    if (t < 31) {
      int nxt = cur ^ 1;
#pragma unroll
      for (int jj = 0; jj < 4; ++jj) {
        *(uint4*)((char*)Ks[nxt] + ((w * 4 + jj) * 64 + l) * 16) = kst[jj];
        *(uint4*)((char*)Vs[nxt] + ((l & 7) * 256 + w * 32 + jj * 8 + (l >> 3)) * 16) = vst[jj];
      }
    }
    __syncthreads();
  }

  // epilogue
  float rinv[16];
#pragma unroll
  for (int r = 0; r < 16; ++r) {
    float lr = __shfl(l_s, 4 * g + (r & 3) + 8 * (r >> 2));
    rinv[r] = 1.f / lr;
  }
#pragma unroll
  for (int dt = 0; dt < 4; ++dt) {
    int col = n * 256 + dh * 128 + dt * 32 + m;
#pragma unroll
    for (int r = 0; r < 16; ++r) {
      int rowq = q0 + qg * 32 + 4 * g + (r & 3) + 8 * (r >> 2);
      comb[(size_t)(b * 2048 + rowq) * 1024 + col] = f2bf(ao[dt][r] * rinv[r]);
    }
  }
}

extern "C" void kernel_launch(void* const* d_in, const int* in_sizes, int n_in,
                              void* d_out, int out_size, void* d_ws, size_t ws_size,
                              hipStream_t stream) {
  const float* x  = (const float*)d_in[0];
  const float* Wq = (const float*)d_in[1];
  const float* bq = (const float*)d_in[2];
  const float* Wk = (const float*)d_in[3];
  const float* bk = (const float*)d_in[4];
  const float* Wv = (const float*)d_in[5];
  const float* bv = (const float*)d_in[6];
  const float* Wo = (const float*)d_in[7];
  const float* bo = (const float*)d_in[8];

  const size_t MB = 1ull << 20;
  char* ws = (char*)d_ws;
  unsigned short* xb  = (unsigned short*)(ws);            // 32MB (reused as comb)
  unsigned short* Wqt = (unsigned short*)(ws + 32 * MB);  // 2MB, contiguous B [3072][1024] starts here
  unsigned short* Wkt = (unsigned short*)(ws + 34 * MB);  // 2MB
  unsigned short* Wvt = (unsigned short*)(ws + 36 * MB);  // 2MB
  unsigned short* Wot = (unsigned short*)(ws + 38 * MB);  // 0.5MB
  unsigned short* Qb  = (unsigned short*)(ws + 40 * MB);  // 32MB
  unsigned short* Kg  = (unsigned short*)(ws + 72 * MB);  // 32MB (fragment-plane layout)
  unsigned short* Vt  = (unsigned short*)(ws + 104 * MB); // 32MB (end: 136MB)
  unsigned short* comb = xb;

  k_cvt<<<2048, 256, 0, stream>>>(x, xb, 16384 * 1024 / 4);
  dim3 trb(32, 8);
  k_tr<<<dim3(8, 32, 4), trb, 0, stream>>>(Wq, Wqt, 1024, 256);
  k_tr<<<dim3(8, 32, 4), trb, 0, stream>>>(Wk, Wkt, 1024, 256);
  k_tr<<<dim3(8, 32, 4), trb, 0, stream>>>(Wv, Wvt, 1024, 256);
  k_tr<<<dim3(8, 32, 1), trb, 0, stream>>>(Wo, Wot, 1024, 256);

  const float qscale = 0.0625f * 1.44269504088896f;  // 1/sqrt(256) * log2(e)
  k_gemmqkv<<<dim3(12, 128), 512, 0, stream>>>(xb, Wqt, bq, bk, bv, Qb, Kg, Vt, qscale);

  k_attn<<<512, 512, 0, stream>>>(Qb, Kg, Vt, comb);

  k_gemmo<<<dim3(1, 128), 512, 0, stream>>>(comb, Wot, bo, (float*)d_out);
}

// Round 5
// 396.458 us; speedup vs baseline: 3.1404x; 1.0971x over previous
//
#include <hip/hip_runtime.h>
#include <hip/hip_bf16.h>

typedef __attribute__((ext_vector_type(8))) short bf16x8;
typedef __attribute__((ext_vector_type(4))) float f32x4;
typedef __attribute__((ext_vector_type(16))) float f32x16;

#define DEVI __device__ __forceinline__

DEVI unsigned short f2bf(float f) {
  union { float f; unsigned u; } v; v.f = f;
  unsigned r = v.u + 0x7FFFu + ((v.u >> 16) & 1u);
  return (unsigned short)(r >> 16);
}

DEVI void gload16(const void* g, void* l) {
  __builtin_amdgcn_global_load_lds(
      (const __attribute__((address_space(1))) unsigned int*)g,
      (__attribute__((address_space(3))) unsigned int*)l, 16, 0, 0);
}

// ---------------- fp32 -> bf16 convert ----------------
__global__ void k_cvt(const float* __restrict__ in, unsigned short* __restrict__ out, int n4) {
  int i = blockIdx.x * blockDim.x + threadIdx.x;
  int stride = gridDim.x * blockDim.x;
  for (; i < n4; i += stride) {
    float4 v = ((const float4*)in)[i];
    ushort4 o;
    o.x = f2bf(v.x); o.y = f2bf(v.y); o.z = f2bf(v.z); o.w = f2bf(v.w);
    ((ushort4*)out)[i] = o;
  }
}

// ------------- transpose [R][C] f32 -> [C][R] bf16, batched over blockIdx.z -------------
__global__ void k_tr(const float* __restrict__ in, unsigned short* __restrict__ out, int R, int C) {
  __shared__ float t[32][33];
  size_t base = (size_t)blockIdx.z * R * C;
  int r0 = blockIdx.y * 32, c0 = blockIdx.x * 32;
  int tx = threadIdx.x, ty = threadIdx.y;
  for (int i = 0; i < 32; i += 8)
    t[ty + i][tx] = in[base + (size_t)(r0 + ty + i) * C + (c0 + tx)];
  __syncthreads();
  for (int i = 0; i < 32; i += 8)
    out[base + (size_t)(c0 + ty + i) * R + (r0 + tx)] = f2bf(t[tx][ty + i]);
}

// ---------------- fused QKV GEMM: [16384,1024] x [3072,1024]^T ----------------
// Epilogue: Q (bf16 rowmajor, *qscale), K (fragment-plane layout),
// V (granule layout matching attention LDS image: [nb][tile][plane 8][d 256] x 16B,
//    kv(p,j) = (p>>1)*16 + 8*(j>>2) + (p&1)*4 + (j&3) within the 64-kv tile).
__global__ __launch_bounds__(512, 4) void k_gemmqkv(
    const unsigned short* __restrict__ A,
    const unsigned short* __restrict__ B,
    const float* __restrict__ bq, const float* __restrict__ bk,
    const float* __restrict__ bv,
    unsigned short* __restrict__ Qb, unsigned short* __restrict__ Kg,
    unsigned short* __restrict__ Vt, float qscale)
{
  __shared__ unsigned short As[128 * 64];
  __shared__ unsigned short Bs[256 * 64];
  int tid = threadIdx.x;
  int w = tid >> 6, l = tid & 63;
  int lg = l >> 4, lm = l & 15;
  int wr = w >> 2, wc = w & 3;
  int row0 = blockIdx.y * 128, col0 = blockIdx.x * 256;

  const f32x4 fz = {0.f, 0.f, 0.f, 0.f};
  f32x4 acc[4][4];
  for (int i = 0; i < 4; i++) for (int j = 0; j < 4; j++) acc[i][j] = fz;

  for (int t = 0; t < 16; ++t) {
    int k0 = t << 6;
    __syncthreads();
#pragma unroll
    for (int j = 0; j < 2; ++j) {
      int ch = j * 512 + tid;
      int row = ch >> 3, cirp = (ch & 7) ^ (row & 7);
      gload16(A + (size_t)(row0 + row) * 1024 + k0 + cirp * 8,
              As + (size_t)(j * 512 + w * 64) * 8);
    }
#pragma unroll
    for (int j = 0; j < 4; ++j) {
      int ch = j * 512 + tid;
      int row = ch >> 3, cirp = (ch & 7) ^ (row & 7);
      gload16(B + (size_t)(col0 + row) * 1024 + k0 + cirp * 8,
              Bs + (size_t)(j * 512 + w * 64) * 8);
    }
    __syncthreads();
#pragma unroll
    for (int kt = 0; kt < 2; ++kt) {
      bf16x8 bfr[4];
#pragma unroll
      for (int ni = 0; ni < 4; ++ni) {
        int r = wc * 64 + ni * 16 + lm;
        bfr[ni] = *(const bf16x8*)((const char*)Bs + r * 128 + ((kt * 64 + lg * 16) ^ ((r & 7) << 4)));
      }
#pragma unroll
      for (int mi = 0; mi < 4; ++mi) {
        int r = wr * 64 + mi * 16 + lm;
        bf16x8 afr = *(const bf16x8*)((const char*)As + r * 128 + ((kt * 64 + lg * 16) ^ ((r & 7) << 4)));
#pragma unroll
        for (int ni = 0; ni < 4; ++ni)
          acc[mi][ni] = __builtin_amdgcn_mfma_f32_16x16x32_bf16(afr, bfr[ni], acc[mi][ni], 0, 0, 0);
      }
    }
  }

  int sel = col0 >> 10;                 // block-uniform: 0=Q, 1=K, 2=V
  const float* bb = sel == 0 ? bq : (sel == 1 ? bk : bv);
#pragma unroll
  for (int mi = 0; mi < 4; ++mi) {
#pragma unroll
    for (int ni = 0; ni < 4; ++ni) {
#pragma unroll
      for (int q = 0; q < 4; ++q) {
        int rg = row0 + wr * 64 + mi * 16 + lg * 4 + q;
        int cg = col0 + wc * 64 + ni * 16 + lm;
        int cl = cg & 1023;
        float val = acc[mi][ni][q] + bb[cl];
        int bI = rg >> 11, s = rg & 2047;
        int nn = cl >> 8, d = cl & 255;
        if (sel == 0) {
          Qb[(size_t)rg * 1024 + cl] = f2bf(val * qscale);
        } else if (sel == 1) {
          Kg[((size_t)((nn * 8 + bI) * 32 + (d >> 3))) * 16384 + (size_t)s * 8 + (d & 7)] = f2bf(val);
        } else {
          int t2 = s >> 6, u = s & 63;
          int p = ((u >> 4) & 3) * 2 + ((u >> 2) & 1);
          int jv = ((u >> 3) & 1) * 4 + (u & 3);
          Vt[(((size_t)(nn * 8 + bI) * 32 + t2) * 2048 + p * 256 + d) * 8 + jv] = f2bf(val);
        }
      }
    }
  }
}

// ---------------- output GEMM: [16384,1024] x [256,1024]^T -> fp32 + bo ----------------
__global__ __launch_bounds__(512, 4) void k_gemmo(
    const unsigned short* __restrict__ A,
    const unsigned short* __restrict__ B,
    const float* __restrict__ bias,
    float* __restrict__ Cout)
{
  __shared__ unsigned short As[128 * 64];
  __shared__ unsigned short Bs[256 * 64];
  int tid = threadIdx.x;
  int w = tid >> 6, l = tid & 63;
  int lg = l >> 4, lm = l & 15;
  int wr = w >> 2, wc = w & 3;
  int row0 = blockIdx.y * 128;

  const f32x4 fz = {0.f, 0.f, 0.f, 0.f};
  f32x4 acc[4][4];
  for (int i = 0; i < 4; i++) for (int j = 0; j < 4; j++) acc[i][j] = fz;

  for (int t = 0; t < 16; ++t) {
    int k0 = t << 6;
    __syncthreads();
#pragma unroll
    for (int j = 0; j < 2; ++j) {
      int ch = j * 512 + tid;
      int row = ch >> 3, cirp = (ch & 7) ^ (row & 7);
      gload16(A + (size_t)(row0 + row) * 1024 + k0 + cirp * 8,
              As + (size_t)(j * 512 + w * 64) * 8);
    }
#pragma unroll
    for (int j = 0; j < 4; ++j) {
      int ch = j * 512 + tid;
      int row = ch >> 3, cirp = (ch & 7) ^ (row & 7);
      gload16(B + (size_t)(row) * 1024 + k0 + cirp * 8,
              Bs + (size_t)(j * 512 + w * 64) * 8);
    }
    __syncthreads();
#pragma unroll
    for (int kt = 0; kt < 2; ++kt) {
      bf16x8 bfr[4];
#pragma unroll
      for (int ni = 0; ni < 4; ++ni) {
        int r = wc * 64 + ni * 16 + lm;
        bfr[ni] = *(const bf16x8*)((const char*)Bs + r * 128 + ((kt * 64 + lg * 16) ^ ((r & 7) << 4)));
      }
#pragma unroll
      for (int mi = 0; mi < 4; ++mi) {
        int r = wr * 64 + mi * 16 + lm;
        bf16x8 afr = *(const bf16x8*)((const char*)As + r * 128 + ((kt * 64 + lg * 16) ^ ((r & 7) << 4)));
#pragma unroll
        for (int ni = 0; ni < 4; ++ni)
          acc[mi][ni] = __builtin_amdgcn_mfma_f32_16x16x32_bf16(afr, bfr[ni], acc[mi][ni], 0, 0, 0);
      }
    }
  }

#pragma unroll
  for (int mi = 0; mi < 4; ++mi)
#pragma unroll
    for (int ni = 0; ni < 4; ++ni)
#pragma unroll
      for (int q = 0; q < 4; ++q) {
        int rg = row0 + wr * 64 + mi * 16 + lg * 4 + q;
        int cg = wc * 64 + ni * 16 + lm;
        Cout[(size_t)rg * 256 + cg] = acc[mi][ni][q] + bias[cg];
      }
}

// ---------------- flash attention ----------------
// block = 128 q rows of one (n,b); 8 waves: qg=w&3 (32 q rows), dh=w>>2 (d half).
// K LDS [dslot 32][kv 64] granules; V LDS [plane 8][d 256] granules (16B each).
// Both staged via global_load_lds (linear, conflict-free). Double-buffered,
// ONE barrier per kv-iter. All LDS reads contiguous-512B per half-wave.
__global__ __launch_bounds__(512, 2) void k_attn(
    const unsigned short* __restrict__ Qb,
    const unsigned short* __restrict__ Kg,
    const unsigned short* __restrict__ Vt,
    unsigned short* __restrict__ comb)
{
  __shared__ unsigned short Ks[2][2048 * 8];
  __shared__ unsigned short Vs[2][2048 * 8];

  int i = blockIdx.x;
  int c = i & 7, j = i >> 3;
  int nbb = c + 8 * (j >> 4);
  int qt = j & 15;
  int n = nbb >> 3, b = nbb & 7;
  int q0 = qt * 128;

  int tid = threadIdx.x;
  int w = tid >> 6, l = tid & 63;
  int m = l & 31, g = l >> 5;
  int qg = w & 3, dh = w >> 2;

  // Q fragments: rows q0+qg*32+m, k-pack d = ks*16 + g*8 + j
  bf16x8 qf[16];
  {
    const unsigned short* qbase = Qb + (size_t)(b * 2048 + q0 + qg * 32 + m) * 1024 + n * 256 + g * 8;
#pragma unroll
    for (int ks = 0; ks < 16; ++ks)
      qf[ks] = *(const bf16x8*)(qbase + ks * 16);
  }

  f32x16 ao[4];
#pragma unroll
  for (int dt = 0; dt < 4; ++dt)
#pragma unroll
    for (int r = 0; r < 16; ++r) ao[dt][r] = 0.f;
  float m_s = -1e30f, l_s = 0.f;

  // staging source lanes: K plane w*4+jj, kv granule l; V granule w*256+jj*64+l
  const unsigned short* kpl = Kg + (((size_t)(n * 8 + b) * 32 + w * 4) * 16384) + (size_t)l * 8;
  const unsigned short* vpl = Vt + ((size_t)(n * 8 + b) * 65536 + w * 256 + l) * 8;

#pragma unroll
  for (int jj = 0; jj < 4; ++jj) {
    gload16(kpl + jj * 16384, Ks[0] + (w * 256 + jj * 64) * 8);
    gload16(vpl + jj * 512,   Vs[0] + (w * 256 + jj * 64) * 8);
  }
  __syncthreads();

  for (int t = 0; t < 32; ++t) {
    int cur = t & 1;
    const unsigned short* Kc = Ks[cur];
    const unsigned short* Vc = Vs[cur];

    if (t < 31) {
      int tn = t + 1;
#pragma unroll
      for (int jj = 0; jj < 4; ++jj) {
        gload16(kpl + jj * 16384 + tn * 512, Ks[cur ^ 1] + (w * 256 + jj * 64) * 8);
        gload16(vpl + (size_t)tn * 16384 + jj * 512, Vs[cur ^ 1] + (w * 256 + jj * 64) * 8);
      }
    }

    // QK^T swapped: s0/s1 = S[kv 0..31 / 32..63][q=lane&31]
    f32x16 s0, s1;
#pragma unroll
    for (int r = 0; r < 16; ++r) { s0[r] = 0.f; s1[r] = 0.f; }
    __builtin_amdgcn_s_setprio(1);
#pragma unroll
    for (int ks = 0; ks < 16; ++ks) {
      bf16x8 k0 = *(const bf16x8*)(Kc + ((2 * ks + g) * 64 + m) * 8);
      bf16x8 k1 = *(const bf16x8*)(Kc + ((2 * ks + g) * 64 + 32 + m) * 8);
      s0 = __builtin_amdgcn_mfma_f32_32x32x16_bf16(k0, qf[ks], s0, 0, 0, 0);
      s1 = __builtin_amdgcn_mfma_f32_32x32x16_bf16(k1, qf[ks], s1, 0, 0, 0);
    }
    __builtin_amdgcn_s_setprio(0);

    // online softmax (exp2 domain; Q pre-scaled)
    float vm = s0[0];
#pragma unroll
    for (int r = 1; r < 16; ++r) vm = fmaxf(vm, s0[r]);
#pragma unroll
    for (int r = 0; r < 16; ++r) vm = fmaxf(vm, s1[r]);
    vm = fmaxf(vm, __shfl_xor(vm, 32));

    if (__any(vm > m_s + 8.f)) {
      float mn = fmaxf(m_s, vm);
      float f = exp2f(m_s - mn);
      m_s = mn; l_s *= f;
#pragma unroll
      for (int r = 0; r < 16; ++r) {
        float fr = __shfl(f, 4 * g + (r & 3) + 8 * (r >> 2));
        ao[0][r] *= fr; ao[1][r] *= fr; ao[2][r] *= fr; ao[3][r] *= fr;
      }
    }

    float p0[16], p1[16];
    float rs = 0.f;
#pragma unroll
    for (int r = 0; r < 16; ++r) {
      p0[r] = exp2f(s0[r] - m_s);
      p1[r] = exp2f(s1[r] - m_s);
      rs += p0[r] + p1[r];
    }
    rs += __shfl_xor(rs, 32);
    l_s += rs;

    // pack P: pa[ks2] elem j <- P[kv = ks2*16 + 8*(j>>2) + 4g + (j&3)]
    bf16x8 pa[4];
#pragma unroll
    for (int ks2 = 0; ks2 < 4; ++ks2) {
#pragma unroll
      for (int jj = 0; jj < 8; ++jj) {
        int ridx = ((ks2 & 1) * 2 + (jj >> 2)) * 4 + (jj & 3);
        float pv = (ks2 < 2) ? p0[ridx] : p1[ridx];
        pa[ks2][jj] = (short)f2bf(pv);
      }
    }

    // PV: ao[dt] += P[q32][kv64] * V[kv64][d32]
    __builtin_amdgcn_s_setprio(1);
#pragma unroll
    for (int dt = 0; dt < 4; ++dt) {
      int vrow = dh * 128 + dt * 32 + m;
#pragma unroll
      for (int ks2 = 0; ks2 < 4; ++ks2) {
        bf16x8 vf = *(const bf16x8*)(Vc + ((2 * ks2 + g) * 256 + vrow) * 8);
        ao[dt] = __builtin_amdgcn_mfma_f32_32x32x16_bf16(pa[ks2], vf, ao[dt], 0, 0, 0);
      }
    }
    __builtin_amdgcn_s_setprio(0);

    __syncthreads();
  }

  // epilogue
  float rinv[16];
#pragma unroll
  for (int r = 0; r < 16; ++r) {
    float lr = __shfl(l_s, 4 * g + (r & 3) + 8 * (r >> 2));
    rinv[r] = 1.f / lr;
  }
#pragma unroll
  for (int dt = 0; dt < 4; ++dt) {
    int col = n * 256 + dh * 128 + dt * 32 + m;
#pragma unroll
    for (int r = 0; r < 16; ++r) {
      int rowq = q0 + qg * 32 + 4 * g + (r & 3) + 8 * (r >> 2);
      comb[(size_t)(b * 2048 + rowq) * 1024 + col] = f2bf(ao[dt][r] * rinv[r]);
    }
  }
}

extern "C" void kernel_launch(void* const* d_in, const int* in_sizes, int n_in,
                              void* d_out, int out_size, void* d_ws, size_t ws_size,
                              hipStream_t stream) {
  const float* x  = (const float*)d_in[0];
  const float* Wq = (const float*)d_in[1];
  const float* bq = (const float*)d_in[2];
  const float* Wk = (const float*)d_in[3];
  const float* bk = (const float*)d_in[4];
  const float* Wv = (const float*)d_in[5];
  const float* bv = (const float*)d_in[6];
  const float* Wo = (const float*)d_in[7];
  const float* bo = (const float*)d_in[8];

  const size_t MB = 1ull << 20;
  char* ws = (char*)d_ws;
  unsigned short* xb  = (unsigned short*)(ws);            // 32MB (reused as comb)
  unsigned short* Wqt = (unsigned short*)(ws + 32 * MB);  // 2MB, contiguous B [3072][1024] starts here
  unsigned short* Wkt = (unsigned short*)(ws + 34 * MB);  // 2MB
  unsigned short* Wvt = (unsigned short*)(ws + 36 * MB);  // 2MB
  unsigned short* Wot = (unsigned short*)(ws + 38 * MB);  // 0.5MB
  unsigned short* Qb  = (unsigned short*)(ws + 40 * MB);  // 32MB
  unsigned short* Kg  = (unsigned short*)(ws + 72 * MB);  // 32MB (fragment-plane layout)
  unsigned short* Vt  = (unsigned short*)(ws + 104 * MB); // 32MB (granule layout, end: 136MB)
  unsigned short* comb = xb;

  k_cvt<<<2048, 256, 0, stream>>>(x, xb, 16384 * 1024 / 4);
  dim3 trb(32, 8);
  k_tr<<<dim3(8, 32, 4), trb, 0, stream>>>(Wq, Wqt, 1024, 256);
  k_tr<<<dim3(8, 32, 4), trb, 0, stream>>>(Wk, Wkt, 1024, 256);
  k_tr<<<dim3(8, 32, 4), trb, 0, stream>>>(Wv, Wvt, 1024, 256);
  k_tr<<<dim3(8, 32, 1), trb, 0, stream>>>(Wo, Wot, 1024, 256);

  const float qscale = 0.0625f * 1.44269504088896f;  // 1/sqrt(256) * log2(e)
  k_gemmqkv<<<dim3(12, 128), 512, 0, stream>>>(xb, Wqt, bq, bk, bv, Qb, Kg, Vt, qscale);

  k_attn<<<512, 512, 0, stream>>>(Qb, Kg, Vt, comb);

  k_gemmo<<<dim3(1, 128), 512, 0, stream>>>(comb, Wot, bo, (float*)d_out);
}

// Round 6
// 392.350 us; speedup vs baseline: 3.1732x; 1.0105x over previous
//
#include <hip/hip_runtime.h>
#include <hip/hip_bf16.h>

typedef __attribute__((ext_vector_type(8))) short bf16x8;
typedef __attribute__((ext_vector_type(4))) float f32x4;
typedef __attribute__((ext_vector_type(16))) float f32x16;

#define DEVI __device__ __forceinline__

DEVI unsigned short f2bf(float f) {
  union { float f; unsigned u; } v; v.f = f;
  unsigned r = v.u + 0x7FFFu + ((v.u >> 16) & 1u);
  return (unsigned short)(r >> 16);
}

DEVI unsigned cvtpk(float lo, float hi) {
  unsigned r;
  asm("v_cvt_pk_bf16_f32 %0, %1, %2" : "=v"(r) : "v"(lo), "v"(hi));
  return r;
}

DEVI void gload16(const void* g, void* l) {
  __builtin_amdgcn_global_load_lds(
      (const __attribute__((address_space(1))) unsigned int*)g,
      (__attribute__((address_space(3))) unsigned int*)l, 16, 0, 0);
}

// ---------------- fp32 -> bf16 convert ----------------
__global__ void k_cvt(const float* __restrict__ in, unsigned short* __restrict__ out, int n4) {
  int i = blockIdx.x * blockDim.x + threadIdx.x;
  int stride = gridDim.x * blockDim.x;
  for (; i < n4; i += stride) {
    float4 v = ((const float4*)in)[i];
    ushort4 o;
    o.x = f2bf(v.x); o.y = f2bf(v.y); o.z = f2bf(v.z); o.w = f2bf(v.w);
    ((ushort4*)out)[i] = o;
  }
}

// ------------- transpose [R][C] f32 -> [C][R] bf16, batched over blockIdx.z -------------
__global__ void k_tr(const float* __restrict__ in, unsigned short* __restrict__ out, int R, int C) {
  __shared__ float t[32][33];
  size_t base = (size_t)blockIdx.z * R * C;
  int r0 = blockIdx.y * 32, c0 = blockIdx.x * 32;
  int tx = threadIdx.x, ty = threadIdx.y;
  for (int i = 0; i < 32; i += 8)
    t[ty + i][tx] = in[base + (size_t)(r0 + ty + i) * C + (c0 + tx)];
  __syncthreads();
  for (int i = 0; i < 32; i += 8)
    out[base + (size_t)(c0 + ty + i) * R + (r0 + tx)] = f2bf(t[tx][ty + i]);
}

// ---------------- fused QKV GEMM: [16384,1024] x [3072,1024]^T ----------------
__global__ __launch_bounds__(512, 4) void k_gemmqkv(
    const unsigned short* __restrict__ A,
    const unsigned short* __restrict__ B,
    const float* __restrict__ bq, const float* __restrict__ bk,
    const float* __restrict__ bv,
    unsigned short* __restrict__ Qb, unsigned short* __restrict__ Kg,
    unsigned short* __restrict__ Vt, float qscale)
{
  __shared__ unsigned short As[128 * 64];
  __shared__ unsigned short Bs[256 * 64];
  int tid = threadIdx.x;
  int w = tid >> 6, l = tid & 63;
  int lg = l >> 4, lm = l & 15;
  int wr = w >> 2, wc = w & 3;
  int row0 = blockIdx.y * 128, col0 = blockIdx.x * 256;

  const f32x4 fz = {0.f, 0.f, 0.f, 0.f};
  f32x4 acc[4][4];
  for (int i = 0; i < 4; i++) for (int j = 0; j < 4; j++) acc[i][j] = fz;

  for (int t = 0; t < 16; ++t) {
    int k0 = t << 6;
    __syncthreads();
#pragma unroll
    for (int j = 0; j < 2; ++j) {
      int ch = j * 512 + tid;
      int row = ch >> 3, cirp = (ch & 7) ^ (row & 7);
      gload16(A + (size_t)(row0 + row) * 1024 + k0 + cirp * 8,
              As + (size_t)(j * 512 + w * 64) * 8);
    }
#pragma unroll
    for (int j = 0; j < 4; ++j) {
      int ch = j * 512 + tid;
      int row = ch >> 3, cirp = (ch & 7) ^ (row & 7);
      gload16(B + (size_t)(col0 + row) * 1024 + k0 + cirp * 8,
              Bs + (size_t)(j * 512 + w * 64) * 8);
    }
    __syncthreads();
#pragma unroll
    for (int kt = 0; kt < 2; ++kt) {
      bf16x8 bfr[4];
#pragma unroll
      for (int ni = 0; ni < 4; ++ni) {
        int r = wc * 64 + ni * 16 + lm;
        bfr[ni] = *(const bf16x8*)((const char*)Bs + r * 128 + ((kt * 64 + lg * 16) ^ ((r & 7) << 4)));
      }
#pragma unroll
      for (int mi = 0; mi < 4; ++mi) {
        int r = wr * 64 + mi * 16 + lm;
        bf16x8 afr = *(const bf16x8*)((const char*)As + r * 128 + ((kt * 64 + lg * 16) ^ ((r & 7) << 4)));
#pragma unroll
        for (int ni = 0; ni < 4; ++ni)
          acc[mi][ni] = __builtin_amdgcn_mfma_f32_16x16x32_bf16(afr, bfr[ni], acc[mi][ni], 0, 0, 0);
      }
    }
  }

  int sel = col0 >> 10;                 // block-uniform: 0=Q, 1=K, 2=V
  const float* bb = sel == 0 ? bq : (sel == 1 ? bk : bv);
#pragma unroll
  for (int mi = 0; mi < 4; ++mi) {
#pragma unroll
    for (int ni = 0; ni < 4; ++ni) {
#pragma unroll
      for (int q = 0; q < 4; ++q) {
        int rg = row0 + wr * 64 + mi * 16 + lg * 4 + q;
        int cg = col0 + wc * 64 + ni * 16 + lm;
        int cl = cg & 1023;
        float val = acc[mi][ni][q] + bb[cl];
        int bI = rg >> 11, s = rg & 2047;
        int nn = cl >> 8, d = cl & 255;
        if (sel == 0) {
          Qb[(size_t)rg * 1024 + cl] = f2bf(val * qscale);
        } else if (sel == 1) {
          Kg[((size_t)((nn * 8 + bI) * 32 + (d >> 3))) * 16384 + (size_t)s * 8 + (d & 7)] = f2bf(val);
        } else {
          int t2 = s >> 6, u = s & 63;
          int p = ((u >> 4) & 3) * 2 + ((u >> 2) & 1);
          int jv = ((u >> 3) & 1) * 4 + (u & 3);
          Vt[(((size_t)(nn * 8 + bI) * 32 + t2) * 2048 + p * 256 + d) * 8 + jv] = f2bf(val);
        }
      }
    }
  }
}

// ---------------- output GEMM: [16384,1024] x [256,1024]^T -> fp32 + bo ----------------
__global__ __launch_bounds__(512, 4) void k_gemmo(
    const unsigned short* __restrict__ A,
    const unsigned short* __restrict__ B,
    const float* __restrict__ bias,
    float* __restrict__ Cout)
{
  __shared__ unsigned short As[128 * 64];
  __shared__ unsigned short Bs[256 * 64];
  int tid = threadIdx.x;
  int w = tid >> 6, l = tid & 63;
  int lg = l >> 4, lm = l & 15;
  int wr = w >> 2, wc = w & 3;
  int row0 = blockIdx.y * 128;

  const f32x4 fz = {0.f, 0.f, 0.f, 0.f};
  f32x4 acc[4][4];
  for (int i = 0; i < 4; i++) for (int j = 0; j < 4; j++) acc[i][j] = fz;

  for (int t = 0; t < 16; ++t) {
    int k0 = t << 6;
    __syncthreads();
#pragma unroll
    for (int j = 0; j < 2; ++j) {
      int ch = j * 512 + tid;
      int row = ch >> 3, cirp = (ch & 7) ^ (row & 7);
      gload16(A + (size_t)(row0 + row) * 1024 + k0 + cirp * 8,
              As + (size_t)(j * 512 + w * 64) * 8);
    }
#pragma unroll
    for (int j = 0; j < 4; ++j) {
      int ch = j * 512 + tid;
      int row = ch >> 3, cirp = (ch & 7) ^ (row & 7);
      gload16(B + (size_t)(row) * 1024 + k0 + cirp * 8,
              Bs + (size_t)(j * 512 + w * 64) * 8);
    }
    __syncthreads();
#pragma unroll
    for (int kt = 0; kt < 2; ++kt) {
      bf16x8 bfr[4];
#pragma unroll
      for (int ni = 0; ni < 4; ++ni) {
        int r = wc * 64 + ni * 16 + lm;
        bfr[ni] = *(const bf16x8*)((const char*)Bs + r * 128 + ((kt * 64 + lg * 16) ^ ((r & 7) << 4)));
      }
#pragma unroll
      for (int mi = 0; mi < 4; ++mi) {
        int r = wr * 64 + mi * 16 + lm;
        bf16x8 afr = *(const bf16x8*)((const char*)As + r * 128 + ((kt * 64 + lg * 16) ^ ((r & 7) << 4)));
#pragma unroll
        for (int ni = 0; ni < 4; ++ni)
          acc[mi][ni] = __builtin_amdgcn_mfma_f32_16x16x32_bf16(afr, bfr[ni], acc[mi][ni], 0, 0, 0);
      }
    }
  }

#pragma unroll
  for (int mi = 0; mi < 4; ++mi)
#pragma unroll
    for (int ni = 0; ni < 4; ++ni)
#pragma unroll
      for (int q = 0; q < 4; ++q) {
        int rg = row0 + wr * 64 + mi * 16 + lg * 4 + q;
        int cg = wc * 64 + ni * 16 + lm;
        Cout[(size_t)rg * 256 + cg] = acc[mi][ni][q] + bias[cg];
      }
}

// ---------------- flash attention (pipelined) ----------------
// iter t: [K-prefetch(t+1)] [QK(t)] [PV(t-1)] [sync] [V-prefetch(t+1)] [softmax(t)->pa(t)] [sync]
__global__ __launch_bounds__(512, 2) void k_attn(
    const unsigned short* __restrict__ Qb,
    const unsigned short* __restrict__ Kg,
    const unsigned short* __restrict__ Vt,
    unsigned short* __restrict__ comb)
{
  __shared__ unsigned short Ks[2][2048 * 8];
  __shared__ unsigned short Vs[2][2048 * 8];

  int i = blockIdx.x;
  int c = i & 7, j = i >> 3;
  int nbb = c + 8 * (j >> 4);
  int qt = j & 15;
  int n = nbb >> 3, b = nbb & 7;
  int q0 = qt * 128;

  int tid = threadIdx.x;
  int w = tid >> 6, l = tid & 63;
  int m = l & 31, g = l >> 5;
  int qg = w & 3, dh = w >> 2;

  bf16x8 qf[16];
  {
    const unsigned short* qbase = Qb + (size_t)(b * 2048 + q0 + qg * 32 + m) * 1024 + n * 256 + g * 8;
#pragma unroll
    for (int ks = 0; ks < 16; ++ks)
      qf[ks] = *(const bf16x8*)(qbase + ks * 16);
  }

  f32x16 ao[4];
#pragma unroll
  for (int dt = 0; dt < 4; ++dt)
#pragma unroll
    for (int r = 0; r < 16; ++r) ao[dt][r] = 0.f;
  float m_s = -1e30f, l_s = 0.f;
  bf16x8 pa[4];

  const unsigned short* kpl = Kg + (((size_t)(n * 8 + b) * 32 + w * 4) * 16384) + (size_t)l * 8;
  const unsigned short* vpl = Vt + ((size_t)(n * 8 + b) * 65536 + w * 256 + l) * 8;

#pragma unroll
  for (int jj = 0; jj < 4; ++jj) {
    gload16(kpl + jj * 16384, Ks[0] + (w * 256 + jj * 64) * 8);
    gload16(vpl + jj * 512,   Vs[0] + (w * 256 + jj * 64) * 8);
  }
  __syncthreads();

  for (int t = 0; t < 32; ++t) {
    int cur = t & 1;
    const unsigned short* Kc = Ks[cur];

    // K-prefetch(t+1): targets Ks[cur^1], last read at iter t-1 (safe).
    if (t < 31) {
      int tn = t + 1;
#pragma unroll
      for (int jj = 0; jj < 4; ++jj)
        gload16(kpl + jj * 16384 + tn * 512, Ks[cur ^ 1] + (w * 256 + jj * 64) * 8);
    }

    // QK^T swapped: s0/s1 = S[kv 0..31 / 32..63][q=lane&31]
    f32x16 s0, s1;
#pragma unroll
    for (int r = 0; r < 16; ++r) { s0[r] = 0.f; s1[r] = 0.f; }
    __builtin_amdgcn_s_setprio(1);
#pragma unroll
    for (int ks = 0; ks < 16; ++ks) {
      bf16x8 k0 = *(const bf16x8*)(Kc + ((2 * ks + g) * 64 + m) * 8);
      bf16x8 k1 = *(const bf16x8*)(Kc + ((2 * ks + g) * 64 + 32 + m) * 8);
      s0 = __builtin_amdgcn_mfma_f32_32x32x16_bf16(k0, qf[ks], s0, 0, 0, 0);
      s1 = __builtin_amdgcn_mfma_f32_32x32x16_bf16(k1, qf[ks], s1, 0, 0, 0);
    }

    // PV(t-1): reads Vs[cur^1] (V(t-1)); pa packed with m_(t-1); ao currently m_(t-1)-scaled.
    if (t > 0) {
      const unsigned short* Vp = Vs[cur ^ 1];
#pragma unroll
      for (int dt = 0; dt < 4; ++dt) {
        int vrow = dh * 128 + dt * 32 + m;
#pragma unroll
        for (int ks2 = 0; ks2 < 4; ++ks2) {
          bf16x8 vf = *(const bf16x8*)(Vp + ((2 * ks2 + g) * 256 + vrow) * 8);
          ao[dt] = __builtin_amdgcn_mfma_f32_32x32x16_bf16(pa[ks2], vf, ao[dt], 0, 0, 0);
        }
      }
    }
    __builtin_amdgcn_s_setprio(0);

    // mid barrier: all waves done reading Vs[cur^1]; drains K-prefetch (cheap).
    __syncthreads();

    // V-prefetch(t+1) into Vs[cur^1]
    if (t < 31) {
      int tn = t + 1;
#pragma unroll
      for (int jj = 0; jj < 4; ++jj)
        gload16(vpl + (size_t)tn * 16384 + jj * 512, Vs[cur ^ 1] + (w * 256 + jj * 64) * 8);
    }

    // ---- softmax(t) (exp2 domain; Q pre-scaled) ----
    float tm[16];
#pragma unroll
    for (int r = 0; r < 16; ++r) tm[r] = fmaxf(s0[r], s1[r]);
#pragma unroll
    for (int d = 8; d > 0; d >>= 1)
#pragma unroll
      for (int r = 0; r < d; ++r) tm[r] = fmaxf(tm[r], tm[r + d]);
    float vm = fmaxf(tm[0], __shfl_xor(tm[0], 32));

    if (__any(vm > m_s + 8.f)) {
      float mn = fmaxf(m_s, vm);
      float f = exp2f(m_s - mn);
      m_s = mn; l_s *= f;
#pragma unroll
      for (int r = 0; r < 16; ++r) {
        float fr = __shfl(f, 4 * g + (r & 3) + 8 * (r >> 2));
        ao[0][r] *= fr; ao[1][r] *= fr; ao[2][r] *= fr; ao[3][r] *= fr;
      }
    }

    float p0[16], p1[16];
#pragma unroll
    for (int r = 0; r < 16; ++r) {
      p0[r] = exp2f(s0[r] - m_s);
      p1[r] = exp2f(s1[r] - m_s);
    }
    float ts[16];
#pragma unroll
    for (int r = 0; r < 16; ++r) ts[r] = p0[r] + p1[r];
#pragma unroll
    for (int d = 8; d > 0; d >>= 1)
#pragma unroll
      for (int r = 0; r < d; ++r) ts[r] += ts[r + d];
    l_s += ts[0] + __shfl_xor(ts[0], 32);

    // pack P via v_cvt_pk_bf16_f32: pa[0]=p0[0..7], pa[1]=p0[8..15], pa[2]=p1[0..7], pa[3]=p1[8..15]
    {
      union { unsigned u[4]; bf16x8 v; } w0, w1, w2, w3;
#pragma unroll
      for (int wd = 0; wd < 4; ++wd) {
        w0.u[wd] = cvtpk(p0[2 * wd], p0[2 * wd + 1]);
        w1.u[wd] = cvtpk(p0[8 + 2 * wd], p0[8 + 2 * wd + 1]);
        w2.u[wd] = cvtpk(p1[2 * wd], p1[2 * wd + 1]);
        w3.u[wd] = cvtpk(p1[8 + 2 * wd], p1[8 + 2 * wd + 1]);
      }
      pa[0] = w0.v; pa[1] = w1.v; pa[2] = w2.v; pa[3] = w3.v;
    }

    // end barrier: drains V-prefetch; next iter reads Ks/Vs[cur^1].
    __syncthreads();
  }

  // final PV(31): V(31) lives in Vs[1]
  {
    const unsigned short* Vp = Vs[1];
    __builtin_amdgcn_s_setprio(1);
#pragma unroll
    for (int dt = 0; dt < 4; ++dt) {
      int vrow = dh * 128 + dt * 32 + m;
#pragma unroll
      for (int ks2 = 0; ks2 < 4; ++ks2) {
        bf16x8 vf = *(const bf16x8*)(Vp + ((2 * ks2 + g) * 256 + vrow) * 8);
        ao[dt] = __builtin_amdgcn_mfma_f32_32x32x16_bf16(pa[ks2], vf, ao[dt], 0, 0, 0);
      }
    }
    __builtin_amdgcn_s_setprio(0);
  }

  // epilogue
  float rinv[16];
#pragma unroll
  for (int r = 0; r < 16; ++r) {
    float lr = __shfl(l_s, 4 * g + (r & 3) + 8 * (r >> 2));
    rinv[r] = 1.f / lr;
  }
#pragma unroll
  for (int dt = 0; dt < 4; ++dt) {
    int col = n * 256 + dh * 128 + dt * 32 + m;
#pragma unroll
    for (int r = 0; r < 16; ++r) {
      int rowq = q0 + qg * 32 + 4 * g + (r & 3) + 8 * (r >> 2);
      comb[(size_t)(b * 2048 + rowq) * 1024 + col] = f2bf(ao[dt][r] * rinv[r]);
    }
  }
}

extern "C" void kernel_launch(void* const* d_in, const int* in_sizes, int n_in,
                              void* d_out, int out_size, void* d_ws, size_t ws_size,
                              hipStream_t stream) {
  const float* x  = (const float*)d_in[0];
  const float* Wq = (const float*)d_in[1];
  const float* bq = (const float*)d_in[2];
  const float* Wk = (const float*)d_in[3];
  const float* bk = (const float*)d_in[4];
  const float* Wv = (const float*)d_in[5];
  const float* bv = (const float*)d_in[6];
  const float* Wo = (const float*)d_in[7];
  const float* bo = (const float*)d_in[8];

  const size_t MB = 1ull << 20;
  char* ws = (char*)d_ws;
  unsigned short* xb  = (unsigned short*)(ws);            // 32MB (reused as comb)
  unsigned short* Wqt = (unsigned short*)(ws + 32 * MB);  // 2MB, contiguous B [3072][1024] starts here
  unsigned short* Wkt = (unsigned short*)(ws + 34 * MB);  // 2MB
  unsigned short* Wvt = (unsigned short*)(ws + 36 * MB);  // 2MB
  unsigned short* Wot = (unsigned short*)(ws + 38 * MB);  // 0.5MB
  unsigned short* Qb  = (unsigned short*)(ws + 40 * MB);  // 32MB
  unsigned short* Kg  = (unsigned short*)(ws + 72 * MB);  // 32MB (fragment-plane layout)
  unsigned short* Vt  = (unsigned short*)(ws + 104 * MB); // 32MB (granule layout, end: 136MB)
  unsigned short* comb = xb;

  k_cvt<<<2048, 256, 0, stream>>>(x, xb, 16384 * 1024 / 4);
  dim3 trb(32, 8);
  k_tr<<<dim3(8, 32, 4), trb, 0, stream>>>(Wq, Wqt, 1024, 256);
  k_tr<<<dim3(8, 32, 4), trb, 0, stream>>>(Wk, Wkt, 1024, 256);
  k_tr<<<dim3(8, 32, 4), trb, 0, stream>>>(Wv, Wvt, 1024, 256);
  k_tr<<<dim3(8, 32, 1), trb, 0, stream>>>(Wo, Wot, 1024, 256);

  const float qscale = 0.0625f * 1.44269504088896f;  // 1/sqrt(256) * log2(e)
  k_gemmqkv<<<dim3(12, 128), 512, 0, stream>>>(xb, Wqt, bq, bk, bv, Qb, Kg, Vt, qscale);

  k_attn<<<512, 512, 0, stream>>>(Qb, Kg, Vt, comb);

  k_gemmo<<<dim3(1, 128), 512, 0, stream>>>(comb, Wot, bo, (float*)d_out);
}